// Round 2
// 18128.197 us; speedup vs baseline: 1.2547x; 1.2547x over previous
//
#include <hip/hip_runtime.h>
#include <math.h>

// GPT-2 small forward: B=2, T=1024, C=768, H=12, D=64, L=12, FF=3072, V=50257
#define TT 1024
#define CC 768
#define HH 12
#define DD 64
#define FF_DIM 3072
#define VV 50257
#define LL 12
#define BT_ROWS 2048   // B*T

typedef __attribute__((ext_vector_type(8))) short bf16x8;
typedef __attribute__((ext_vector_type(4))) float f32x4;

// split one fp32 pair into packed bf16-hi (trunc) and bf16-lo (residual, trunc).
// h: low ushort = bf16(a), high ushort = bf16(b). Same for l with residuals.
__device__ __forceinline__ void split2(float a, float b, unsigned& h, unsigned& l) {
  unsigned ua = __float_as_uint(a), ub = __float_as_uint(b);
  h = (ua >> 16) | (ub & 0xFFFF0000u);
  float ra = a - __uint_as_float(ua & 0xFFFF0000u);
  float rb = b - __uint_as_float(ub & 0xFFFF0000u);
  l = (__float_as_uint(ra) >> 16) | (__float_as_uint(rb) & 0xFFFF0000u);
}

// ---------------- embedding ----------------
__global__ __launch_bounds__(256) void embed_kernel(
    const int* __restrict__ idx, const float* __restrict__ tok,
    const float* __restrict__ pos, float* __restrict__ x) {
  int row = blockIdx.x;                 // 0..2047
  int t = row & (TT - 1);
  int token = idx[row];
  const float* tp = tok + (size_t)token * CC;
  const float* pp = pos + (size_t)t * CC;
  float* xp = x + (size_t)row * CC;
  for (int c = threadIdx.x; c < CC; c += 256)
    xp[c] = tp[c] + pp[c];
}

// ---------------- layernorm ----------------
__global__ __launch_bounds__(256) void ln_kernel(
    const float* __restrict__ x, const float* __restrict__ s,
    const float* __restrict__ b, float* __restrict__ out) {
  int row = blockIdx.x;
  const float* xr = x + (size_t)row * CC;
  float vals[3];
  float sum = 0.f, sq = 0.f;
#pragma unroll
  for (int i = 0; i < 3; ++i) {
    float v = xr[threadIdx.x + 256 * i];
    vals[i] = v;
    sum += v;
    sq += v * v;
  }
#pragma unroll
  for (int off = 32; off; off >>= 1) {
    sum += __shfl_xor(sum, off);
    sq += __shfl_xor(sq, off);
  }
  __shared__ float red[8];
  int lane = threadIdx.x & 63, wid = threadIdx.x >> 6;
  if (lane == 0) { red[wid] = sum; red[4 + wid] = sq; }
  __syncthreads();
  sum = red[0] + red[1] + red[2] + red[3];
  sq = red[4] + red[5] + red[6] + red[7];
  float mean = sum * (1.0f / CC);
  float var = sq * (1.0f / CC) - mean * mean;
  float rstd = rsqrtf(var + 1e-5f);
  float* op = out + (size_t)row * CC;
#pragma unroll
  for (int i = 0; i < 3; ++i) {
    int c = threadIdx.x + 256 * i;
    op[c] = (vals[i] - mean) * rstd * s[c] + b[c];
  }
}

// ---------------- MFMA split-bf16 GEMM ----------------
// out[M,N] = act(A[M,K] @ W[K,N] + bias) (+ resid), fp32 in/out.
// A, W split into bf16 hi/lo in LDS; 3-term MFMA (hh + hl + lh) gives ~fp32 accuracy.
// Tile: BM = IBLK*32 (64 or 128), BN = 128, BK = 32.  256 thr = 4 waves.
// Fragment layout (mfma_f32_16x16x32_bf16): A row = lane&15, k = 8*(lane>>4)+j (contiguous 8);
// B col = lane&15, same k; C/D col = lane&15, row = (lane>>4)*4 + reg  [m89-verified].
template <int IBLK, bool GELU, bool ALIGNED_N>
__global__ __launch_bounds__(256, 2) void gemm_mfma(
    const float* __restrict__ A, const float* __restrict__ W,
    const float* __restrict__ bias, const float* __restrict__ resid,
    float* __restrict__ out, int M, int N, int K) {
  constexpr int BM = IBLK * 32;
  constexpr int LDK = 40;   // pad 32 -> 40 ushorts to spread LDS banks
  __shared__ unsigned short Ah[BM][LDK], Al[BM][LDK];
  __shared__ unsigned short Bh[128][LDK], Bl[128][LDK];

  int tid = threadIdx.x;
  int lane = tid & 63;
  int w = tid >> 6;
  int wr = w >> 1, wc = w & 1;
  int m0 = blockIdx.y * BM;
  int n0 = blockIdx.x * 128;

  // A staging map: BM*32 floats / 256 threads
  constexpr int AF = BM * 32 / 256;   // 16 (BM=128) or 8 (BM=64) floats per thread
  constexpr int TPR = 32 / AF;        // threads per A row
  int ar = tid / TPR;
  int ac = (tid % TPR) * AF;
  // B staging map (transposing): thread owns one n-column, 16 k values
  int bn = tid & 127;
  int bk = (tid >> 7) * 16;           // 0 or 16
  int gbn = n0 + bn;

  f32x4 acc[IBLK][4] = {};

  for (int k0 = 0; k0 < K; k0 += 32) {
    // ---- stage A (vectorized loads, split to hi/lo bf16) ----
    {
      const float* ap = A + (size_t)(m0 + ar) * K + k0 + ac;
      float af[AF];
#pragma unroll
      for (int p = 0; p < AF / 4; ++p) {
        float4 v = *(const float4*)(ap + p * 4);
        af[p * 4 + 0] = v.x; af[p * 4 + 1] = v.y;
        af[p * 4 + 2] = v.z; af[p * 4 + 3] = v.w;
      }
      unsigned hs[AF / 2], ls[AF / 2];
#pragma unroll
      for (int p = 0; p < AF / 2; ++p) split2(af[2 * p], af[2 * p + 1], hs[p], ls[p]);
#pragma unroll
      for (int p = 0; p < AF / 8; ++p) {
        *(uint4*)&Ah[ar][ac + p * 8] = make_uint4(hs[4 * p], hs[4 * p + 1], hs[4 * p + 2], hs[4 * p + 3]);
        *(uint4*)&Al[ar][ac + p * 8] = make_uint4(ls[4 * p], ls[4 * p + 1], ls[4 * p + 2], ls[4 * p + 3]);
      }
    }
    // ---- stage B transposed: W[k][n] -> Bh/Bl[n][k] ----
    {
      float bv[16];
      if (ALIGNED_N || gbn < N) {
        const float* wp = W + (size_t)(k0 + bk) * N + gbn;   // coalesced: 64 lanes = 64 consecutive n
#pragma unroll
        for (int j = 0; j < 16; ++j) bv[j] = wp[(size_t)j * N];
      } else {
#pragma unroll
        for (int j = 0; j < 16; ++j) bv[j] = 0.f;
      }
      unsigned hs[8], ls[8];
#pragma unroll
      for (int p = 0; p < 8; ++p) split2(bv[2 * p], bv[2 * p + 1], hs[p], ls[p]);
      *(uint4*)&Bh[bn][bk + 0] = make_uint4(hs[0], hs[1], hs[2], hs[3]);
      *(uint4*)&Bh[bn][bk + 8] = make_uint4(hs[4], hs[5], hs[6], hs[7]);
      *(uint4*)&Bl[bn][bk + 0] = make_uint4(ls[0], ls[1], ls[2], ls[3]);
      *(uint4*)&Bl[bn][bk + 8] = make_uint4(ls[4], ls[5], ls[6], ls[7]);
    }
    __syncthreads();

    // ---- fragments + MFMA ----
    int kb = (lane >> 4) * 8;
    int rb = wr * (IBLK * 16) + (lane & 15);
    int cb = wc * 64 + (lane & 15);
    bf16x8 fah[IBLK], fal[IBLK], fbh[4], fbl[4];
#pragma unroll
    for (int i = 0; i < IBLK; ++i) {
      fah[i] = *(const bf16x8*)&Ah[rb + i * 16][kb];
      fal[i] = *(const bf16x8*)&Al[rb + i * 16][kb];
    }
#pragma unroll
    for (int j = 0; j < 4; ++j) {
      fbh[j] = *(const bf16x8*)&Bh[cb + j * 16][kb];
      fbl[j] = *(const bf16x8*)&Bl[cb + j * 16][kb];
    }
    // three passes so each acc reuse is ~16 MFMAs apart (no dependency stall)
#pragma unroll
    for (int i = 0; i < IBLK; ++i)
#pragma unroll
      for (int j = 0; j < 4; ++j)
        acc[i][j] = __builtin_amdgcn_mfma_f32_16x16x32_bf16(fah[i], fbh[j], acc[i][j], 0, 0, 0);
#pragma unroll
    for (int i = 0; i < IBLK; ++i)
#pragma unroll
      for (int j = 0; j < 4; ++j)
        acc[i][j] = __builtin_amdgcn_mfma_f32_16x16x32_bf16(fah[i], fbl[j], acc[i][j], 0, 0, 0);
#pragma unroll
    for (int i = 0; i < IBLK; ++i)
#pragma unroll
      for (int j = 0; j < 4; ++j)
        acc[i][j] = __builtin_amdgcn_mfma_f32_16x16x32_bf16(fal[i], fbh[j], acc[i][j], 0, 0, 0);
    __syncthreads();
  }

  // ---- epilogue ----
  int r0 = m0 + wr * (IBLK * 16) + (lane >> 4) * 4;
  int c0 = n0 + wc * 64 + (lane & 15);
#pragma unroll
  for (int i = 0; i < IBLK; ++i) {
#pragma unroll
    for (int q = 0; q < 4; ++q) {
      int m = r0 + i * 16 + q;
      float* op = out + (size_t)m * N;
      const float* rp = resid ? (resid + (size_t)m * N) : nullptr;
#pragma unroll
      for (int j = 0; j < 4; ++j) {
        int n = c0 + j * 16;
        if (ALIGNED_N || n < N) {
          float v = acc[i][j][q];
          if (bias) v += bias[n];
          if (GELU) v = 0.5f * v * (1.0f + erff(v * 0.70710678118654752f));
          if (rp) v += rp[n];
          op[n] = v;
        }
      }
    }
  }
}

// ---------------- attention: one wave per (b,h,qrow), online softmax ----------------
__global__ __launch_bounds__(256) void attn_kernel(
    const float* __restrict__ qkv, float* __restrict__ y) {
  int lane = threadIdx.x & 63;
  int wid = blockIdx.x * 4 + (threadIdx.x >> 6);  // 0 .. B*H*T-1
  int qr = wid & (TT - 1);
  int bh = wid >> 10;       // b*H + h
  int h = bh % HH;
  int b = bh / HH;
  const float* base = qkv + (size_t)(b * TT) * (3 * CC);
  float q = base[(size_t)qr * (3 * CC) + h * DD + lane] * 0.125f;

  float m = -INFINITY, l = 0.f, acc = 0.f;
  for (int j = 0; j <= qr; ++j) {
    const float* kp = base + (size_t)j * (3 * CC) + CC + h * DD;
    float kd = kp[lane];
    float vd = kp[CC + lane];
    float s = q * kd;
#pragma unroll
    for (int off = 32; off; off >>= 1) s += __shfl_xor(s, off);
    float mn = fmaxf(m, s);
    float sc = __expf(m - mn);
    float p = __expf(s - mn);
    l = l * sc + p;
    acc = acc * sc + p * vd;
    m = mn;
  }
  y[((size_t)(b * TT) + qr) * CC + h * DD + lane] = acc / l;
}

// ---------------- launch ----------------
extern "C" void kernel_launch(void* const* d_in, const int* in_sizes, int n_in,
                              void* d_out, int out_size, void* d_ws, size_t ws_size,
                              hipStream_t stream) {
  const int* idx = (const int*)d_in[0];
  const float* tok_emb = (const float*)d_in[1];
  const float* pos_emb = (const float*)d_in[2];
  const float* ln1_s = (const float*)d_in[3];
  const float* ln1_b = (const float*)d_in[4];
  const float* Wqkv = (const float*)d_in[5];
  const float* bqkv = (const float*)d_in[6];
  const float* Wo = (const float*)d_in[7];
  const float* bo = (const float*)d_in[8];
  const float* ln2_s = (const float*)d_in[9];
  const float* ln2_b = (const float*)d_in[10];
  const float* Wfc = (const float*)d_in[11];
  const float* bfc = (const float*)d_in[12];
  const float* Wpr = (const float*)d_in[13];
  const float* bpr = (const float*)d_in[14];
  const float* lnf_s = (const float*)d_in[15];
  const float* lnf_b = (const float*)d_in[16];
  const float* Whead = (const float*)d_in[17];
  float* logits = (float*)d_out;

  float* ws = (float*)d_ws;
  float* x = ws;                         // 2048*768
  float* h = x + (size_t)BT_ROWS * CC;   // 2048*768
  float* qkv = h + (size_t)BT_ROWS * CC; // 2048*2304
  float* y = qkv + (size_t)BT_ROWS * 3 * CC;   // 2048*768
  float* ffn = y + (size_t)BT_ROWS * CC;       // 2048*3072

  dim3 blk(256);
  embed_kernel<<<BT_ROWS, blk, 0, stream>>>(idx, tok_emb, pos_emb, x);

  for (int l = 0; l < LL; ++l) {
    const float* wqkv = Wqkv + (size_t)l * CC * 3 * CC;
    const float* bq = bqkv + (size_t)l * 3 * CC;
    const float* wo = Wo + (size_t)l * CC * CC;
    const float* bo_ = bo + (size_t)l * CC;
    const float* wfc = Wfc + (size_t)l * CC * FF_DIM;
    const float* bf = bfc + (size_t)l * FF_DIM;
    const float* wpr = Wpr + (size_t)l * FF_DIM * CC;
    const float* bp = bpr + (size_t)l * CC;

    ln_kernel<<<BT_ROWS, blk, 0, stream>>>(x, ln1_s + l * CC, ln1_b + l * CC, h);
    // qkv: M=2048 N=2304 K=768 -> 18x16 blocks, BM=128
    gemm_mfma<4, false, true><<<dim3(3 * CC / 128, BT_ROWS / 128), blk, 0, stream>>>(
        h, wqkv, bq, nullptr, qkv, BT_ROWS, 3 * CC, CC);
    attn_kernel<<<(2 * HH * TT) / 4, blk, 0, stream>>>(qkv, y);
    // attn proj: N=768 -> BM=64 for more blocks (6x32=192)
    gemm_mfma<2, false, true><<<dim3(CC / 128, BT_ROWS / 64), blk, 0, stream>>>(
        y, wo, bo_, x, x, BT_ROWS, CC, CC);
    ln_kernel<<<BT_ROWS, blk, 0, stream>>>(x, ln2_s + l * CC, ln2_b + l * CC, h);
    // fc: N=3072 -> 24x16 blocks, BM=128
    gemm_mfma<4, true, true><<<dim3(FF_DIM / 128, BT_ROWS / 128), blk, 0, stream>>>(
        h, wfc, bf, nullptr, ffn, BT_ROWS, FF_DIM, CC);
    // proj back: N=768 K=3072 -> BM=64
    gemm_mfma<2, false, true><<<dim3(CC / 128, BT_ROWS / 64), blk, 0, stream>>>(
        ffn, wpr, bp, x, x, BT_ROWS, CC, FF_DIM);
  }

  ln_kernel<<<BT_ROWS, blk, 0, stream>>>(x, lnf_s, lnf_b, h);
  // head: N=50257 (unaligned), no bias
  gemm_mfma<4, false, false><<<dim3((VV + 127) / 128, BT_ROWS / 128), blk, 0, stream>>>(
      h, Whead, nullptr, nullptr, logits, BT_ROWS, VV, CC);
}